// Round 1
// baseline (1435.039 us; speedup 1.0000x reference)
//
#include <hip/hip_runtime.h>
#include <hip/hip_bf16.h>

#define DD 4096
#define NTOK 8192

using u16 = unsigned short;

typedef __attribute__((ext_vector_type(8))) short bfrag;   // 8 bf16 = 4 VGPR (MFMA A/B frag)
typedef __attribute__((ext_vector_type(4))) float ffrag;   // 4 f32 (MFMA C/D frag)
typedef __attribute__((ext_vector_type(4))) float f32x4v;

// RNE float -> bf16 (bit math; matches numpy/JAX round-to-nearest-even)
__device__ __forceinline__ u16 f2bf(float f) {
  unsigned u = __float_as_uint(f);
  u += 0x7FFFu + ((u >> 16) & 1u);
  return (u16)(u >> 16);
}
__device__ __forceinline__ float bf2f(u16 u) {
  return __uint_as_float(((unsigned)u) << 16);
}

// async global->LDS, 16B per lane (wave-uniform LDS base + lane*16)
#define GLDS16(g, l)                                                  \
  __builtin_amdgcn_global_load_lds(                                   \
      (__attribute__((address_space(1))) const void*)(g),             \
      (__attribute__((address_space(3))) void*)(l), 16, 0, 0)

// ---------------- split: f32 -> (bf16 hi, bf16 lo) ----------------
__global__ void __launch_bounds__(256) split_bf16_kernel(
    const float* __restrict__ in, u16* __restrict__ hi,
    u16* __restrict__ lo, long n4) {
  long i = (long)blockIdx.x * blockDim.x + threadIdx.x;
  const long stride = (long)gridDim.x * blockDim.x;
  for (; i < n4; i += stride) {
    f32x4v v = reinterpret_cast<const f32x4v*>(in)[i];
    u16 h[4], l[4];
#pragma unroll
    for (int j = 0; j < 4; ++j) {
      float f = v[j];
      u16 hb = f2bf(f);
      h[j] = hb;
      l[j] = f2bf(f - bf2f(hb));
    }
    ushort4 hv, lv;
    hv.x = h[0]; hv.y = h[1]; hv.z = h[2]; hv.w = h[3];
    lv.x = l[0]; lv.y = l[1]; lv.z = l[2]; lv.w = l[3];
    reinterpret_cast<ushort4*>(hi)[i] = hv;
    reinterpret_cast<ushort4*>(lo)[i] = lv;
  }
}

// ---------------- transpose f32 [R][C] -> bf16 [C][R] ----------------
__global__ void __launch_bounds__(256) transpose_bf16_kernel(
    const float* __restrict__ in, u16* __restrict__ out, int R, int C) {
  __shared__ u16 tile[64][65];
  const int bc = blockIdx.x << 6;  // col base in `in`
  const int br = blockIdx.y << 6;  // row base in `in`
  const int tc = threadIdx.x & 63;
  const int tr0 = threadIdx.x >> 6;
#pragma unroll
  for (int p = 0; p < 16; ++p) {
    int r = tr0 + (p << 2);
    tile[tc][r] = f2bf(in[(size_t)(br + r) * C + (bc + tc)]);
  }
  __syncthreads();
#pragma unroll
  for (int p = 0; p < 16; ++p) {
    int orow = tr0 + (p << 2);
    out[(size_t)(bc + orow) * R + (br + tc)] = tile[orow][tc];
  }
}

// ---------------- GEMM C = sum_t A_t * B_t^T  (m97 128^2 structure) ----
// NTERMS==1: A0*B0t.  NTERMS==3: A0*B0t + A1*B0t + A0*B1t (bf16-split fp32 emulation).
// QUANT: epilogue quantizes to nearest centroid, stores bf16; else stores f32.
template <int NTERMS, bool QUANT>
__global__ void __launch_bounds__(256) gemm_bt_kernel(
    const u16* __restrict__ A0, const u16* __restrict__ A1,
    const u16* __restrict__ B0, const u16* __restrict__ B1,
    void* __restrict__ Cout, const float* __restrict__ cent,
    int M, int N, int K) {
  extern __shared__ u16 smem[];
  u16* sA0 = smem;            // [128][32] bf16 = 8KB
  u16* sB0 = smem + 4096;
  u16* sA1 = smem + 8192;     // only NTERMS==3
  u16* sB1 = smem + 12288;

  __shared__ float clut[16];
  const int t = threadIdx.x;
  if (QUANT && t < 16) clut[t] = cent[t];

  // XCD-aware swizzle (nwg % 8 == 0 -> bijective)
  const int nbn = N >> 7;
  const int nwg = (M >> 7) * nbn;
  int wg = blockIdx.x;
  {
    const int cpx = nwg >> 3;
    wg = (wg & 7) * cpx + (wg >> 3);
  }
  const int tm = (wg / nbn) << 7;
  const int tn = (wg % nbn) << 7;

  const int wave = t >> 6;
  const int lane = t & 63;
  const int wr = ((wave >> 1) << 6);   // wave row origin in tile
  const int wc = ((wave & 1) << 6);    // wave col origin in tile
  const int frow = lane & 15;
  const int kslc = lane >> 4;          // k-slice group (0..3)

  // LDS fragment read offsets (elements); frag i adds i*16 rows = i*512 elems
  const int aoff = (wr + frow) * 32 + kslc * 8;
  const int boff = (wc + frow) * 32 + kslc * 8;

  // staging: 128x32 bf16 tile = 8192B = 2 issues x 256 thr x 16B
  // thread t, issue q: row = q*64 + (t>>2), k-elems = (t&3)*8
  const size_t g_col = (size_t)(t & 3) * 8;
  const size_t aGbase = (size_t)(tm + (t >> 2)) * K + g_col;
  const size_t bGbase = (size_t)(tn + (t >> 2)) * K + g_col;
  const int ldsStage = wave * 512;  // elements; + q*2048

  ffrag acc[4][4];
#pragma unroll
  for (int i = 0; i < 4; ++i)
#pragma unroll
    for (int j = 0; j < 4; ++j) acc[i][j] = {0.f, 0.f, 0.f, 0.f};

  for (int kk = 0; kk < K; kk += 32) {
#pragma unroll
    for (int q = 0; q < 2; ++q) {
      const size_t go = (size_t)q * 64 * K + kk;
      const int lo_ = ldsStage + q * 2048;
      GLDS16(A0 + aGbase + go, sA0 + lo_);
      GLDS16(B0 + bGbase + go, sB0 + lo_);
      if constexpr (NTERMS == 3) {
        GLDS16(A1 + aGbase + go, sA1 + lo_);
        GLDS16(B1 + bGbase + go, sB1 + lo_);
      }
    }
    __syncthreads();

#pragma unroll
    for (int term = 0; term < NTERMS; ++term) {
      const u16* sa = (term == 1) ? sA1 : sA0;
      const u16* sb = (term == 2) ? sB1 : sB0;
      bfrag a[4], b[4];
#pragma unroll
      for (int i = 0; i < 4; ++i) {
        a[i] = *reinterpret_cast<const bfrag*>(sa + aoff + i * 512);
        b[i] = *reinterpret_cast<const bfrag*>(sb + boff + i * 512);
      }
#pragma unroll
      for (int ai = 0; ai < 4; ++ai)
#pragma unroll
        for (int bi = 0; bi < 4; ++bi)
          acc[ai][bi] = __builtin_amdgcn_mfma_f32_16x16x32_bf16(
              a[ai], b[bi], acc[ai][bi], 0, 0, 0);
    }
    __syncthreads();
  }

  // epilogue; C/D frag mapping: col = lane&15, row = (lane>>4)*4 + reg
  const int r0 = tm + wr + kslc * 4;
  const int c0 = tn + wc + frow;
  if constexpr (QUANT) {
    u16* Y = reinterpret_cast<u16*>(Cout);
#pragma unroll
    for (int ai = 0; ai < 4; ++ai)
#pragma unroll
      for (int bi = 0; bi < 4; ++bi)
#pragma unroll
        for (int r = 0; r < 4; ++r) {
          float y = acc[ai][bi][r];
          float s = rintf((y + 1.0f) * 7.5f);  // RNE == jnp.round
          int idx = (int)s;
          idx = idx < 0 ? 0 : (idx > 15 ? 15 : idx);
          Y[(size_t)(r0 + ai * 16 + r) * N + (c0 + bi * 16)] = f2bf(clut[idx]);
        }
  } else {
    float* Co = reinterpret_cast<float*>(Cout);
#pragma unroll
    for (int ai = 0; ai < 4; ++ai)
#pragma unroll
      for (int bi = 0; bi < 4; ++bi)
#pragma unroll
        for (int r = 0; r < 4; ++r)
          Co[(size_t)(r0 + ai * 16 + r) * N + (c0 + bi * 16)] = acc[ai][bi][r];
  }
}

extern "C" void kernel_launch(void* const* d_in, const int* in_sizes, int n_in,
                              void* d_out, int out_size, void* d_ws, size_t ws_size,
                              hipStream_t stream) {
  const float* x = (const float*)d_in[0];     // [8192][4096]
  const float* Pi = (const float*)d_in[1];    // [4096][4096]
  const float* cent = (const float*)d_in[2];  // [16]
  float* out = (float*)d_out;                 // [8192][4096]

  const size_t MB = (size_t)1 << 20;
  if (ws_size < 288 * MB) return;  // need 288MB scratch

  char* ws = (char*)d_ws;
  u16* x_hi = (u16*)(ws + 0 * MB);    // 64MB  bf16(x)
  u16* x_lo = (u16*)(ws + 64 * MB);   // 64MB  bf16(x - x_hi)
  u16* p_hi = (u16*)(ws + 128 * MB);  // 32MB  bf16(Pi)
  u16* p_lo = (u16*)(ws + 160 * MB);  // 32MB  bf16(Pi - p_hi)
  u16* piT  = (u16*)(ws + 192 * MB);  // 32MB  bf16(Pi^T)
  u16* yq   = (u16*)(ws + 224 * MB);  // 64MB  bf16(quantize(x @ Pi^T))

  split_bf16_kernel<<<2048, 256, 0, stream>>>(x, x_hi, x_lo, (long)NTOK * DD / 4);
  split_bf16_kernel<<<1024, 256, 0, stream>>>(Pi, p_hi, p_lo, (long)DD * DD / 4);
  transpose_bf16_kernel<<<dim3(DD / 64, DD / 64), 256, 0, stream>>>(Pi, piT, DD, DD);

  const int nwg = (NTOK / 128) * (DD / 128);  // 2048, %8==0
  // y = x @ Pi^T  ~= x_hi*p_hi + x_lo*p_hi + x_hi*p_lo ; quantize -> yq (bf16)
  gemm_bt_kernel<3, true><<<nwg, 256, 32768, stream>>>(
      x_hi, x_lo, p_hi, p_lo, yq, cent, NTOK, DD, DD);
  // out = yq @ Pi  (B^T form via piT)
  gemm_bt_kernel<1, false><<<nwg, 256, 16384, stream>>>(
      yq, nullptr, piT, nullptr, out, nullptr, NTOK, DD, DD);
}

// Round 2
// 1078.156 us; speedup vs baseline: 1.3310x; 1.3310x over previous
//
#include <hip/hip_runtime.h>
#include <hip/hip_bf16.h>

#define DD 4096
#define NTOK 8192

using u16 = unsigned short;

typedef __attribute__((ext_vector_type(8))) short bfrag;   // 8 bf16 = 4 VGPR (MFMA A/B frag)
typedef __attribute__((ext_vector_type(4))) float ffrag;   // 4 f32 (MFMA C/D frag)
typedef __attribute__((ext_vector_type(4))) float f32x4v;

// RNE float -> bf16 (bit math; matches numpy/JAX round-to-nearest-even)
__device__ __forceinline__ u16 f2bf(float f) {
  unsigned u = __float_as_uint(f);
  u += 0x7FFFu + ((u >> 16) & 1u);
  return (u16)(u >> 16);
}
__device__ __forceinline__ float bf2f(u16 u) {
  return __uint_as_float(((unsigned)u) << 16);
}

// async global->LDS, 16B per lane (wave-uniform LDS base + lane*16)
#define GLDS16(g, l)                                                  \
  __builtin_amdgcn_global_load_lds(                                   \
      (__attribute__((address_space(1))) const void*)(g),             \
      (__attribute__((address_space(3))) void*)(l), 16, 0, 0)

#define MEMFENCE() asm volatile("" ::: "memory")

// ---------------- split: f32 -> (bf16 hi, bf16 lo) ----------------
__global__ void __launch_bounds__(256) split_bf16_kernel(
    const float* __restrict__ in, u16* __restrict__ hi,
    u16* __restrict__ lo, long n4) {
  long i = (long)blockIdx.x * blockDim.x + threadIdx.x;
  const long stride = (long)gridDim.x * blockDim.x;
  for (; i < n4; i += stride) {
    f32x4v v = reinterpret_cast<const f32x4v*>(in)[i];
    u16 h[4], l[4];
#pragma unroll
    for (int j = 0; j < 4; ++j) {
      float f = v[j];
      u16 hb = f2bf(f);
      h[j] = hb;
      l[j] = f2bf(f - bf2f(hb));
    }
    ushort4 hv, lv;
    hv.x = h[0]; hv.y = h[1]; hv.z = h[2]; hv.w = h[3];
    lv.x = l[0]; lv.y = l[1]; lv.z = l[2]; lv.w = l[3];
    reinterpret_cast<ushort4*>(hi)[i] = hv;
    reinterpret_cast<ushort4*>(lo)[i] = lv;
  }
}

// ---------------- transpose f32 [R][C] -> bf16 [C][R] ----------------
__global__ void __launch_bounds__(256) transpose_bf16_kernel(
    const float* __restrict__ in, u16* __restrict__ out, int R, int C) {
  __shared__ u16 tile[64][65];
  const int bc = blockIdx.x << 6;
  const int br = blockIdx.y << 6;
  const int tc = threadIdx.x & 63;
  const int tr0 = threadIdx.x >> 6;
#pragma unroll
  for (int p = 0; p < 16; ++p) {
    int r = tr0 + (p << 2);
    tile[tc][r] = f2bf(in[(size_t)(br + r) * C + (bc + tc)]);
  }
  __syncthreads();
#pragma unroll
  for (int p = 0; p < 16; ++p) {
    int orow = tr0 + (p << 2);
    out[(size_t)(bc + orow) * R + (br + tc)] = tile[orow][tc];
  }
}

// ================= 256^2 8-phase GEMM  C = sum_seg A_seg * B_seg^T =========
// NSEG==1: A0*B0^T. NSEG==3: x_hi*p_hi + x_lo*p_hi + x_hi*p_lo via K-concat
// (tile tau: seg=tau>>6 selects pointers). K per segment = 4096, BK=64.
// 8 waves (2M x 4N), per-wave C = 128x64. LDS: 2 buf x (A 32KB + B 32KB).
// Half-tile staging order per tile: [B0,B1,A0,A1], stagger-7, vmcnt(6).
// LDS swizzle: slot XOR, byte_in_row ^= ((row&7)<<4) (3-bit, bits 4-6),
// applied on the global SOURCE of global_load_lds (linear dest) and on
// ds_read addresses (involution).
template <int NSEG, bool QUANT>
__global__ void __launch_bounds__(512, 2) gemm256_kernel(
    const u16* __restrict__ A0, const u16* __restrict__ A1,
    const u16* __restrict__ B0, const u16* __restrict__ B1,
    void* __restrict__ Cout, const float* __restrict__ cent,
    int M, int N) {
  constexpr int NT = NSEG * 64;  // K-tiles of 64
  __shared__ __align__(16) char SM[131072];
  __shared__ float clut[16];
  const int tid = threadIdx.x;
  if (QUANT && tid < 16) clut[tid] = cent[tid];

  // XCD swizzle (nwg = 512, %8==0 -> bijective)
  const int nbn = N >> 8;
  const int nwg = (M >> 8) * nbn;
  int wg = blockIdx.x;
  wg = (wg & 7) * (nwg >> 3) + (wg >> 3);
  const int tm = (wg / nbn) << 8;
  const int tn = (wg % nbn) << 8;

  const int lane = tid & 63;
  const int wv = tid >> 6;
  const int wm = wv >> 2;   // 0..1 : A-half / row group
  const int wn = wv & 3;    // 0..3 : 64-col group
  const int l15 = lane & 15;
  const int kslc = lane >> 4;          // 0..3
  const int cXor = (lane & 7) << 4;    // swizzle XOR for ds_read

  // staging per-thread global offset (elements): row = wv*8 + (lane>>3),
  // col pre-swizzled so linear LDS dest ends up swizzled.
  const size_t thrOff =
      (size_t)(wv * 8 + (lane >> 3)) * 4096 + 8 * ((lane & 7) ^ (lane >> 3));
  const int ldsThr = wv * 1024 + lane * 16;  // bytes within a 16KB half

  auto STAGE = [&](int h) {
    if (h >= 4 * NT) return;
    const int tau = h >> 2, idx = h & 3;
    const int b = tau & 1;
    const int seg = (NSEG == 3) ? (tau >> 6) : 0;
    const size_t ktE = (size_t)(tau & 63) * 64;
    const u16* src;
    char* lds;
    if (idx < 2) {  // B half idx
      const u16* bbase = (NSEG == 3 && seg == 2) ? B1 : B0;
      src = bbase + (size_t)(tn + idx * 128) * 4096 + ktE + thrOff;
      lds = SM + b * 65536 + 32768 + idx * 16384 + ldsThr;
    } else {  // A half idx-2
      const u16* abase = (NSEG == 3 && seg == 1) ? A1 : A0;
      src = abase + (size_t)(tm + (idx - 2) * 128) * 4096 + ktE + thrOff;
      lds = SM + b * 65536 + (idx - 2) * 16384 + ldsThr;
    }
    GLDS16(src, lds);
    GLDS16(src + 262144, lds + 8192);  // +64 rows
  };

// ds_read byte address within arena (swizzled)
#define LDSA(b, f, s)                                                      \
  (*reinterpret_cast<const bfrag*>(                                        \
      SM + (b) * 65536 + wm * 16384 + (((f) * 16 + l15) << 7) +            \
      ((((s) << 6) | (kslc << 4)) ^ cXor)))
#define LDSB(b, f, s)                                                      \
  (*reinterpret_cast<const bfrag*>(                                        \
      SM + (b) * 65536 + 32768 + (wn >> 1) * 16384 +                       \
      ((((wn & 1) * 64) + (f) * 16 + l15) << 7) +                          \
      ((((s) << 6) | (kslc << 4)) ^ cXor)))

  ffrag acc[8][4];
#pragma unroll
  for (int m = 0; m < 8; ++m)
#pragma unroll
    for (int n = 0; n < 4; ++n) acc[m][n] = {0.f, 0.f, 0.f, 0.f};

  // prologue: stage H0..H6 (tile0 complete + tile1 B0,B1,A0)
#pragma unroll
  for (int h = 0; h < 7; ++h) STAGE(h);
  asm volatile("s_waitcnt vmcnt(6)" ::: "memory");  // tile 0 landed
  MEMFENCE();
  __builtin_amdgcn_s_barrier();

  bfrag Af[8][2], Bf[4][2];

  for (int t = 0; t < NT; ++t) {
    const int b = t & 1;
    const int hb = 7 + 4 * t;
#pragma unroll
    for (int p = 0; p < 4; ++p) {
      // ---- ds-load register subtiles (front-loaded per overwrite map:
      //      B all at p0; A m0-3 p0, m4-5 p1, m6-7 p2; nothing at p3)
      if (p == 0) {
#pragma unroll
        for (int n = 0; n < 4; ++n) {
          Bf[n][0] = LDSB(b, n, 0);
          Bf[n][1] = LDSB(b, n, 1);
        }
#pragma unroll
        for (int m = 0; m < 4; ++m) {
          Af[m][0] = LDSA(b, m, 0);
          Af[m][1] = LDSA(b, m, 1);
        }
      } else if (p == 1) {
        Af[4][0] = LDSA(b, 4, 0); Af[4][1] = LDSA(b, 4, 1);
        Af[5][0] = LDSA(b, 5, 0); Af[5][1] = LDSA(b, 5, 1);
      } else if (p == 2) {
        Af[6][0] = LDSA(b, 6, 0); Af[6][1] = LDSA(b, 6, 1);
        Af[7][0] = LDSA(b, 7, 0); Af[7][1] = LDSA(b, 7, 1);
      }
      // ---- stage one half-tile (H_{7+4t+p}); targets are never read this
      //      phase: overwrites land on halves whose reads drained at the
      //      previous phase's lgkmcnt(0)+barrier.
      STAGE(hb + p);
      MEMFENCE();
      __builtin_amdgcn_s_barrier();
      // drain ALL this phase's ds_reads (incl. next-phase A frags) so the
      // next phase's staging may overwrite their LDS source safely.
      asm volatile("s_waitcnt lgkmcnt(0)" ::: "memory");
      __builtin_amdgcn_sched_barrier(0);
      __builtin_amdgcn_s_setprio(1);
      {
        const int m0 = p * 2;
#pragma unroll
        for (int mm = 0; mm < 2; ++mm)
#pragma unroll
          for (int n = 0; n < 4; ++n) {
            acc[m0 + mm][n] = __builtin_amdgcn_mfma_f32_16x16x32_bf16(
                Af[m0 + mm][0], Bf[n][0], acc[m0 + mm][n], 0, 0, 0);
            acc[m0 + mm][n] = __builtin_amdgcn_mfma_f32_16x16x32_bf16(
                Af[m0 + mm][1], Bf[n][1], acc[m0 + mm][n], 0, 0, 0);
          }
      }
      __builtin_amdgcn_s_setprio(0);
      if (p == 3) {
        // counted vmcnt before the tile-end barrier: next tile fully landed
        // (per-wave counter -> must precede the barrier)
        if (t == NT - 2)
          asm volatile("s_waitcnt vmcnt(0)" ::: "memory");
        else if (t < NT - 2)
          asm volatile("s_waitcnt vmcnt(6)" ::: "memory");
      }
      MEMFENCE();
      __builtin_amdgcn_s_barrier();
    }
  }

  // epilogue; C/D frag mapping: col = lane&15, row = (lane>>4)*4 + reg
  const int r0 = tm + wm * 128 + kslc * 4;
  const int c0 = tn + wn * 64 + l15;
  if constexpr (QUANT) {
    u16* Y = reinterpret_cast<u16*>(Cout);
#pragma unroll
    for (int m = 0; m < 8; ++m)
#pragma unroll
      for (int n = 0; n < 4; ++n)
#pragma unroll
        for (int r = 0; r < 4; ++r) {
          float y = acc[m][n][r];
          float s = rintf((y + 1.0f) * 7.5f);  // RNE == jnp.round
          int idx = (int)s;
          idx = idx < 0 ? 0 : (idx > 15 ? 15 : idx);
          Y[(size_t)(r0 + m * 16 + r) * N + (c0 + n * 16)] = f2bf(clut[idx]);
        }
  } else {
    float* Co = reinterpret_cast<float*>(Cout);
#pragma unroll
    for (int m = 0; m < 8; ++m)
#pragma unroll
      for (int n = 0; n < 4; ++n)
#pragma unroll
        for (int r = 0; r < 4; ++r)
          Co[(size_t)(r0 + m * 16 + r) * N + (c0 + n * 16)] = acc[m][n][r];
  }
#undef LDSA
#undef LDSB
}

extern "C" void kernel_launch(void* const* d_in, const int* in_sizes, int n_in,
                              void* d_out, int out_size, void* d_ws, size_t ws_size,
                              hipStream_t stream) {
  const float* x = (const float*)d_in[0];     // [8192][4096]
  const float* Pi = (const float*)d_in[1];    // [4096][4096]
  const float* cent = (const float*)d_in[2];  // [16]
  float* out = (float*)d_out;                 // [8192][4096]

  const size_t MB = (size_t)1 << 20;
  if (ws_size < 288 * MB) return;  // need 288MB scratch

  char* ws = (char*)d_ws;
  u16* x_hi = (u16*)(ws + 0 * MB);    // 64MB  bf16(x)
  u16* x_lo = (u16*)(ws + 64 * MB);   // 64MB  bf16(x - x_hi)
  u16* p_hi = (u16*)(ws + 128 * MB);  // 32MB  bf16(Pi)
  u16* p_lo = (u16*)(ws + 160 * MB);  // 32MB  bf16(Pi - p_hi)
  u16* piT  = (u16*)(ws + 192 * MB);  // 32MB  bf16(Pi^T)
  u16* yq   = (u16*)(ws + 224 * MB);  // 64MB  bf16(quantize(x @ Pi^T))

  split_bf16_kernel<<<2048, 256, 0, stream>>>(x, x_hi, x_lo, (long)NTOK * DD / 4);
  split_bf16_kernel<<<1024, 256, 0, stream>>>(Pi, p_hi, p_lo, (long)DD * DD / 4);
  transpose_bf16_kernel<<<dim3(DD / 64, DD / 64), 256, 0, stream>>>(Pi, piT, DD, DD);

  const int nwg = (NTOK / 256) * (DD / 256);  // 512, %8==0
  // y = x @ Pi^T  ~= x_hi*p_hi + x_lo*p_hi + x_hi*p_lo ; quantize -> yq (bf16)
  gemm256_kernel<3, true><<<nwg, 512, 0, stream>>>(
      x_hi, x_lo, p_hi, p_lo, yq, cent, NTOK, DD);
  // out = yq @ Pi  (B^T form via piT)
  gemm256_kernel<1, false><<<nwg, 512, 0, stream>>>(
      yq, nullptr, piT, nullptr, out, nullptr, NTOK, DD);
}